// Round 3
// baseline (60.974 us; speedup 1.0000x reference)
//
#include <hip/hip_runtime.h>
#include <hip/hip_bf16.h>

#define BB 16
#define LCTX 2048
#define DDIM 1024
#define QDIM 1024
#define HDIM 256
#define NEGV -10000.0f

typedef __attribute__((ext_vector_type(8))) short short8;
typedef __attribute__((ext_vector_type(4))) float f32x4;

__device__ inline unsigned short f2bf(float x) {
    unsigned int u = __float_as_uint(x);
    unsigned int r = (u + 0x7fffu + ((u >> 16) & 1u)) >> 16;
    return (unsigned short)r;
}

// ---------------- K1: fused prep ----------------
// bid <  1024 : qproj[b][h] = query[b] . Wq[h] + b1[h]   (4 h per block)
// 1024..1279  : Wc row (h = bid-1024) -> bf16, chunks pre-swizzled for LDS
// bid == 1280 : w2 = g * v / ||v||
__global__ __launch_bounds__(256) void k_prep(const float* __restrict__ query,
                                              const float* __restrict__ W1,
                                              const float* __restrict__ b1,
                                              const float* __restrict__ v,
                                              const float* __restrict__ g,
                                              float* __restrict__ qproj,
                                              unsigned short* __restrict__ Wc_sw,
                                              float* __restrict__ w2) {
    int bid = blockIdx.x;
    if (bid < 1024) {
        int b = bid >> 6;
        int hq = bid & 63;
        int wid = threadIdx.x >> 6, lane = threadIdx.x & 63;
        int h = hq * 4 + wid;
        const float* q = query + b * QDIM;
        const float* w = W1 + (size_t)h * (DDIM + QDIM) + DDIM;
        float s = 0.f;
        #pragma unroll 4
        for (int k = lane; k < QDIM; k += 64) s += q[k] * w[k];
        #pragma unroll
        for (int o = 32; o; o >>= 1) s += __shfl_down(s, o);
        if (lane == 0) qproj[b * HDIM + h] = s + b1[h];
    } else if (bid < 1280) {
        int h = bid - 1024;
        const float* src = W1 + (size_t)h * (DDIM + QDIM);
        int hx = h & 7;
        for (int d = threadIdx.x; d < DDIM; d += 256) {
            int kt = d >> 6;
            int s  = (d >> 3) & 7;      // 16B chunk within 64-col k-tile
            int dl = d & 7;
            int dp = (kt << 6) + ((s ^ hx) << 3) + dl;
            Wc_sw[h * DDIM + dp] = f2bf(src[d]);
        }
    } else {
        __shared__ float red[256];
        float vv = (threadIdx.x < HDIM) ? v[threadIdx.x] : 0.f;
        red[threadIdx.x] = vv * vv;
        __syncthreads();
        for (int o = 128; o; o >>= 1) {
            if (threadIdx.x < o) red[threadIdx.x] += red[threadIdx.x + o];
            __syncthreads();
        }
        float nrm = sqrtf(red[0]);
        if (threadIdx.x < HDIM) w2[threadIdx.x] = g[0] * vv / nrm;
    }
}

// ---------------- K2: 32-row tile: score GEMM + tanh + exp + partial GEMV ----------------
// grid 1024 -> 4 blocks/CU (LDS 36 KB), ~50% occupancy target
__global__ __launch_bounds__(256, 4) void k_score(const float* __restrict__ ctx,
                                                  const unsigned short* __restrict__ Wc_sw,
                                                  const float* __restrict__ qproj,
                                                  const float* __restrict__ w2,
                                                  const float* __restrict__ b2,
                                                  const int* __restrict__ mask,
                                                  float* __restrict__ e_ws,
                                                  float* __restrict__ esum_ws,
                                                  float* __restrict__ part) {
    __shared__ unsigned short At[32 * 64];    // 4 KB, XOR-swizzled
    __shared__ unsigned short Wt[256 * 64];   // 32 KB, pre-swizzled in global
    int tid = threadIdx.x;
    int wid = tid >> 6, lane = tid & 63;
    int hl = lane & 15, lhi = lane >> 4;
    int bid = blockIdx.x;
    int row0 = bid * 32;
    int b = row0 >> 11;

    float qp[4], wv[4];
    #pragma unroll
    for (int ht = 0; ht < 4; ht++) {
        int h = wid * 64 + ht * 16 + hl;
        qp[ht] = qproj[b * HDIM + h];
        wv[ht] = w2[h];
    }

    f32x4 acc[2][4];
    #pragma unroll
    for (int mt = 0; mt < 2; mt++)
        #pragma unroll
        for (int ht = 0; ht < 4; ht++)
            acc[mt][ht] = (f32x4){0.f, 0.f, 0.f, 0.f};

    int srow = tid >> 3;            // 0..31 tile row this thread stages
    int c    = tid & 7;             // 16B chunk within 64-col k-tile
    const float* csrc = ctx + (size_t)(row0 + srow) * DDIM + c * 8;
    int sx = srow & 7;
    unsigned short* adst = At + srow * 64 + ((c ^ sx) << 3);

    for (int kt = 0; kt < 16; kt++) {
        // stage W tile: 32 KB via global_load_lds (linear dest; src pre-swizzled)
        #pragma unroll
        for (int i = 0; i < 8; i++) {
            int n = i * 256 + tid;
            const unsigned short* gsrc = Wc_sw + (size_t)(n >> 3) * DDIM + kt * 64 + (n & 7) * 8;
            __builtin_amdgcn_global_load_lds(
                (const __attribute__((address_space(1))) unsigned int*)gsrc,
                (__attribute__((address_space(3))) unsigned int*)(Wt + (i * 256 + (tid & ~63)) * 8),
                16, 0, 0);
        }
        // stage ctx tile: f32 -> bf16 -> swizzled LDS (32 B / thread)
        const float* cp = csrc + kt * 64;
        float4 cv0 = *(const float4*)(cp + 0);
        float4 cv1 = *(const float4*)(cp + 4);
        short8 p0 = { (short)f2bf(cv0.x), (short)f2bf(cv0.y), (short)f2bf(cv0.z), (short)f2bf(cv0.w),
                      (short)f2bf(cv1.x), (short)f2bf(cv1.y), (short)f2bf(cv1.z), (short)f2bf(cv1.w) };
        *(short8*)adst = p0;
        __syncthreads();

        #pragma unroll
        for (int ks = 0; ks < 2; ks++) {
            int s = ks * 4 + lhi;
            short8 af[2], bfr[4];
            #pragma unroll
            for (int mt = 0; mt < 2; mt++) {
                int m = mt * 16 + hl;
                af[mt] = *(const short8*)(At + m * 64 + ((s ^ (m & 7)) << 3));
            }
            #pragma unroll
            for (int ht = 0; ht < 4; ht++) {
                int h = wid * 64 + ht * 16 + hl;
                bfr[ht] = *(const short8*)(Wt + h * 64 + ((s ^ (h & 7)) << 3));
            }
            #pragma unroll
            for (int mt = 0; mt < 2; mt++)
                #pragma unroll
                for (int ht = 0; ht < 4; ht++)
                    acc[mt][ht] = __builtin_amdgcn_mfma_f32_16x16x32_bf16(af[mt], bfr[ht], acc[mt][ht], 0, 0, 0);
        }
        __syncthreads();
    }

    // ---- epilogue 1: tanh + w2 dot, reduce 16 lanes, cross-wave via LDS ----
    float* sb  = (float*)At;        // 128 floats (cross-wave partials)
    float* sbe = sb + 128;          // 32 floats (e per row)
    #pragma unroll
    for (int mt = 0; mt < 2; mt++) {
        #pragma unroll
        for (int r = 0; r < 4; r++) {
            float partial = 0.f;
            #pragma unroll
            for (int ht = 0; ht < 4; ht++) {
                float x = acc[mt][ht][r] + qp[ht];
                x = fminf(fmaxf(x, -15.f), 15.f);
                float e = __expf(2.f * x);
                partial += (e - 1.f) / (e + 1.f) * wv[ht];
            }
            #pragma unroll
            for (int o = 1; o < 16; o <<= 1) partial += __shfl_xor(partial, o);
            if (hl == 0) sb[wid * 32 + mt * 16 + lhi * 4 + r] = partial;
        }
    }
    __syncthreads();

    // ---- epilogue 2: final score -> e = exp(score) (masked -> 0) ----
    if (tid < 32) {
        float s = sb[tid] + sb[32 + tid] + sb[64 + tid] + sb[96 + tid] + b2[0];
        int grow = row0 + tid;
        int bb = grow >> 11, ll = grow & 2047;
        float e = (mask[bb * 2048 + ll] == 1) ? 0.f : __expf(s);
        e_ws[grow] = e;
        sbe[tid] = e;
        float tot = e;
        #pragma unroll
        for (int o = 16; o; o >>= 1) tot += __shfl_down(tot, o);
        if (tid == 0) esum_ws[bid] = tot;
    }
    __syncthreads();

    // ---- epilogue 3: partial GEMV  part[bid][d] = sum_l e_l * ctx[row0+l][d] ----
    // re-reads the block's own 32x1024 f32 tile (128 KB) -> L2/L3-hot
    {
        int d0 = tid * 4;
        const float* cb = ctx + (size_t)row0 * DDIM + d0;
        float4 a = {0.f, 0.f, 0.f, 0.f};
        #pragma unroll 8
        for (int l = 0; l < 32; l++) {
            float el = sbe[l];
            float4 cc = *(const float4*)(cb + (size_t)l * DDIM);
            a.x += el * cc.x; a.y += el * cc.y; a.z += el * cc.z; a.w += el * cc.w;
        }
        *(float4*)(part + (size_t)bid * DDIM + d0) = a;
    }
}

// ---------------- K3: normalize -> out_exp, out_p ----------------
__global__ __launch_bounds__(256) void k_norm(const float* __restrict__ e_ws,
                                              const float* __restrict__ esum_ws,
                                              const float* __restrict__ part,
                                              float* __restrict__ out_exp,
                                              float* __restrict__ out_p) {
    int b = blockIdx.x, dc = blockIdx.y;
    int tid = threadIdx.x;
    float se = 0.f;
    #pragma unroll
    for (int j = 0; j < 64; j++) se += esum_ws[b * 64 + j];
    float inv = 1.f / se;
    if (tid < 128) {
        int d = dc * 128 + tid;
        float s = 0.f;
        #pragma unroll
        for (int j = 0; j < 64; j++) s += part[(size_t)(b * 64 + j) * DDIM + d];
        out_exp[b * DDIM + d] = s * inv;
    }
    int l = dc * 256 + tid;
    out_p[b * LCTX + l] = e_ws[b * LCTX + l] * inv;
}

extern "C" void kernel_launch(void* const* d_in, const int* in_sizes, int n_in,
                              void* d_out, int out_size, void* d_ws, size_t ws_size,
                              hipStream_t stream) {
    const float* ctx   = (const float*)d_in[0];
    const float* query = (const float*)d_in[1];
    const int*   mask  = (const int*)d_in[2];
    const float* W1    = (const float*)d_in[3];
    const float* b1    = (const float*)d_in[4];
    const float* v     = (const float*)d_in[5];
    const float* g     = (const float*)d_in[6];
    const float* b2    = (const float*)d_in[7];
    float* out_exp = (float*)d_out;              // [16,1024]
    float* out_p   = (float*)d_out + 16384;      // [16,2048]

    char* ws = (char*)d_ws;
    unsigned short* Wc_sw = (unsigned short*)ws;          // 512 KB
    float* qproj = (float*)(ws + 524288);                 // 16 KB
    float* w2    = (float*)(ws + 540672);                 // 1 KB
    float* e_ws  = (float*)(ws + 541696);                 // 128 KB (16x2048)
    float* esum  = (float*)(ws + 672768);                 // 4 KB  (1024)
    float* part  = (float*)(ws + 676864);                 // 4 MB  (1024x1024)

    k_prep <<<dim3(1281),   256, 0, stream>>>(query, W1, b1, v, g, qproj, Wc_sw, w2);
    k_score<<<dim3(1024),   256, 0, stream>>>(ctx, Wc_sw, qproj, w2, b2, mask, e_ws, esum, part);
    k_norm <<<dim3(16, 8),  256, 0, stream>>>(e_ws, esum, part, out_exp, out_p);
}

// Round 4
// 59.870 us; speedup vs baseline: 1.0185x; 1.0185x over previous
//
#include <hip/hip_runtime.h>
#include <hip/hip_bf16.h>

#define BB 16
#define LCTX 2048
#define DDIM 1024
#define QDIM 1024
#define HDIM 256
#define NEGV -10000.0f

typedef __attribute__((ext_vector_type(8))) short short8;
typedef __attribute__((ext_vector_type(4))) float f32x4;

__device__ inline unsigned short f2bf(float x) {
    unsigned int u = __float_as_uint(x);
    unsigned int r = (u + 0x7fffu + ((u >> 16) & 1u)) >> 16;
    return (unsigned short)r;
}

// ---------------- K1: fused prep ----------------
__global__ __launch_bounds__(256) void k_prep(const float* __restrict__ query,
                                              const float* __restrict__ W1,
                                              const float* __restrict__ b1,
                                              const float* __restrict__ v,
                                              const float* __restrict__ g,
                                              float* __restrict__ qproj,
                                              unsigned short* __restrict__ Wc_sw,
                                              float* __restrict__ w2) {
    int bid = blockIdx.x;
    if (bid < 1024) {
        int b = bid >> 6;
        int hq = bid & 63;
        int wid = threadIdx.x >> 6, lane = threadIdx.x & 63;
        int h = hq * 4 + wid;
        const float* q = query + b * QDIM;
        const float* w = W1 + (size_t)h * (DDIM + QDIM) + DDIM;
        float s = 0.f;
        #pragma unroll 4
        for (int k = lane; k < QDIM; k += 64) s += q[k] * w[k];
        #pragma unroll
        for (int o = 32; o; o >>= 1) s += __shfl_down(s, o);
        if (lane == 0) qproj[b * HDIM + h] = s + b1[h];
    } else if (bid < 1280) {
        int h = bid - 1024;
        const float* src = W1 + (size_t)h * (DDIM + QDIM);
        int hx = h & 7;
        for (int d = threadIdx.x; d < DDIM; d += 256) {
            int kt = d >> 6;
            int s  = (d >> 3) & 7;
            int dl = d & 7;
            int dp = (kt << 6) + ((s ^ hx) << 3) + dl;
            Wc_sw[h * DDIM + dp] = f2bf(src[d]);
        }
    } else {
        __shared__ float red[256];
        float vv = (threadIdx.x < HDIM) ? v[threadIdx.x] : 0.f;
        red[threadIdx.x] = vv * vv;
        __syncthreads();
        for (int o = 128; o; o >>= 1) {
            if (threadIdx.x < o) red[threadIdx.x] += red[threadIdx.x + o];
            __syncthreads();
        }
        float nrm = sqrtf(red[0]);
        if (threadIdx.x < HDIM) w2[threadIdx.x] = g[0] * vv / nrm;
    }
}

// ---------------- K2: 64-row tile, counted-vmcnt pipelined ----------------
// W: dbuf LDS via global_load_lds, each wave stages ONLY the 64 h-rows it reads
//    -> gload_lds->ds_read dep enforced by the wave's own counted vmcnt.
// ctx: reg-prefetch issued 1 iter ahead; cvt+ds_write after MFMA; barrier-synced.
// Steady-state queue: [W(t).8, ctx(t+1).4, W(t+1).8, ctx(t+2).4]
//   vmcnt(16) before Wt reads, vmcnt(12) before At write, never 0 in loop.
__global__ __launch_bounds__(256, 2) void k_score(const float* __restrict__ ctx,
                                                  const unsigned short* __restrict__ Wc_sw,
                                                  const float* __restrict__ qproj,
                                                  const float* __restrict__ w2,
                                                  const float* __restrict__ b2,
                                                  const int* __restrict__ mask,
                                                  float* __restrict__ e_ws,
                                                  float* __restrict__ esum_ws,
                                                  float* __restrict__ part) {
    __shared__ unsigned short Wt[2][256 * 64];   // 64 KB
    __shared__ unsigned short At[2][64 * 64];    // 16 KB
    int tid = threadIdx.x;
    int wid = tid >> 6, lane = tid & 63;
    int hl = lane & 15, lhi = lane >> 4;
    int bid = blockIdx.x;
    int row0 = bid * 64;
    int b = row0 >> 11;
    int wrow0 = wid * 64;

    f32x4 acc[4][4];
    #pragma unroll
    for (int mt = 0; mt < 4; mt++)
        #pragma unroll
        for (int ht = 0; ht < 4; ht++)
            acc[mt][ht] = (f32x4){0.f, 0.f, 0.f, 0.f};

    int srow = tid >> 2;            // 0..63 staged row
    int c0 = (tid & 3) * 2;         // first 16B chunk index
    int sx = srow & 7;
    const float* csrc = ctx + (size_t)(row0 + srow) * DDIM + (tid & 3) * 16;

    float4 a0, a1, a2, a3, b0, b1, b2v, b3;

#define STAGE_W(BUF, KT) do { \
    _Pragma("unroll") \
    for (int i_ = 0; i_ < 8; i_++) { \
        const unsigned short* gsrc_ = Wc_sw + (size_t)(wrow0 + i_ * 8 + (lane >> 3)) * DDIM + (KT) * 64 + (lane & 7) * 8; \
        __builtin_amdgcn_global_load_lds( \
            (const __attribute__((address_space(1))) unsigned int*)gsrc_, \
            (__attribute__((address_space(3))) unsigned int*)(&Wt[BUF][(wrow0 + i_ * 8) * 64]), \
            16, 0, 0); \
    } } while (0)

#define CTX_ISSUE(KT, R0, R1, R2, R3) do { \
    const float* cp_ = csrc + (KT) * 64; \
    R0 = *(const float4*)(cp_ + 0);  R1 = *(const float4*)(cp_ + 4); \
    R2 = *(const float4*)(cp_ + 8);  R3 = *(const float4*)(cp_ + 12); } while (0)

#define WRITE_A(BUF, U0, U1, U2, U3) do { \
    short8 p0_ = { (short)f2bf(U0.x), (short)f2bf(U0.y), (short)f2bf(U0.z), (short)f2bf(U0.w), \
                   (short)f2bf(U1.x), (short)f2bf(U1.y), (short)f2bf(U1.z), (short)f2bf(U1.w) }; \
    short8 p1_ = { (short)f2bf(U2.x), (short)f2bf(U2.y), (short)f2bf(U2.z), (short)f2bf(U2.w), \
                   (short)f2bf(U3.x), (short)f2bf(U3.y), (short)f2bf(U3.z), (short)f2bf(U3.w) }; \
    *(short8*)(&At[BUF][srow * 64 + (((c0 + 0) ^ sx) << 3)]) = p0_; \
    *(short8*)(&At[BUF][srow * 64 + (((c0 + 1) ^ sx) << 3)]) = p1_; } while (0)

#define COMPUTE(BUF) do { \
    __builtin_amdgcn_s_setprio(1); \
    _Pragma("unroll") \
    for (int ks_ = 0; ks_ < 2; ks_++) { \
        int s_ = ks_ * 4 + lhi; \
        int xc_ = (s_ ^ (hl & 7)) << 3; \
        short8 af_[4], bf_[4]; \
        _Pragma("unroll") \
        for (int mt_ = 0; mt_ < 4; mt_++) \
            af_[mt_] = *(const short8*)(&At[BUF][(mt_ * 16 + hl) * 64 + xc_]); \
        _Pragma("unroll") \
        for (int ht_ = 0; ht_ < 4; ht_++) \
            bf_[ht_] = *(const short8*)(&Wt[BUF][(wrow0 + ht_ * 16 + hl) * 64 + xc_]); \
        _Pragma("unroll") \
        for (int mt_ = 0; mt_ < 4; mt_++) \
            _Pragma("unroll") \
            for (int ht_ = 0; ht_ < 4; ht_++) \
                acc[mt_][ht_] = __builtin_amdgcn_mfma_f32_16x16x32_bf16(af_[mt_], bf_[ht_], acc[mt_][ht_], 0, 0, 0); \
    } \
    __builtin_amdgcn_s_setprio(0); } while (0)

#define BODY(T, R0, R1, R2, R3, U0, U1, U2, U3) do { \
    STAGE_W(((T) + 1) & 1, ((T) + 1) & 15); \
    __builtin_amdgcn_sched_barrier(0); \
    CTX_ISSUE(((T) + 2) & 15, R0, R1, R2, R3); \
    __builtin_amdgcn_sched_barrier(0); \
    asm volatile("s_waitcnt vmcnt(16)" ::: "memory"); \
    __builtin_amdgcn_sched_barrier(0); \
    COMPUTE((T) & 1); \
    asm volatile("s_waitcnt vmcnt(12)" ::: "memory"); \
    __builtin_amdgcn_sched_barrier(0); \
    WRITE_A(((T) + 1) & 1, U0, U1, U2, U3); \
    asm volatile("s_waitcnt lgkmcnt(0)" ::: "memory"); \
    __builtin_amdgcn_s_barrier(); \
    __builtin_amdgcn_sched_barrier(0); } while (0)

    // ---- prologue: stage tile 0, issue ctx(1). queue after: [W0.8, ctx1.4] ----
    CTX_ISSUE(0, a0, a1, a2, a3);
    __builtin_amdgcn_sched_barrier(0);
    STAGE_W(0, 0);
    __builtin_amdgcn_sched_barrier(0);
    asm volatile("s_waitcnt vmcnt(8)" ::: "memory");
    __builtin_amdgcn_sched_barrier(0);
    WRITE_A(0, a0, a1, a2, a3);
    CTX_ISSUE(1, b0, b1, b2v, b3);
    asm volatile("s_waitcnt lgkmcnt(0)" ::: "memory");
    __builtin_amdgcn_s_barrier();
    __builtin_amdgcn_sched_barrier(0);

    BODY(0,  a0, a1, a2, a3,  b0, b1, b2v, b3);
    BODY(1,  b0, b1, b2v, b3, a0, a1, a2, a3);
    BODY(2,  a0, a1, a2, a3,  b0, b1, b2v, b3);
    BODY(3,  b0, b1, b2v, b3, a0, a1, a2, a3);
    BODY(4,  a0, a1, a2, a3,  b0, b1, b2v, b3);
    BODY(5,  b0, b1, b2v, b3, a0, a1, a2, a3);
    BODY(6,  a0, a1, a2, a3,  b0, b1, b2v, b3);
    BODY(7,  b0, b1, b2v, b3, a0, a1, a2, a3);
    BODY(8,  a0, a1, a2, a3,  b0, b1, b2v, b3);
    BODY(9,  b0, b1, b2v, b3, a0, a1, a2, a3);
    BODY(10, a0, a1, a2, a3,  b0, b1, b2v, b3);
    BODY(11, b0, b1, b2v, b3, a0, a1, a2, a3);
    BODY(12, a0, a1, a2, a3,  b0, b1, b2v, b3);
    BODY(13, b0, b1, b2v, b3, a0, a1, a2, a3);
    BODY(14, a0, a1, a2, a3,  b0, b1, b2v, b3);
    BODY(15, b0, b1, b2v, b3, a0, a1, a2, a3);

    // ---- epilogue 1: tanh + w2 dot, reduce 16 lanes, cross-wave via LDS ----
    float qp[4], wv[4];
    #pragma unroll
    for (int ht = 0; ht < 4; ht++) {
        int h = wrow0 + ht * 16 + hl;
        qp[ht] = qproj[b * HDIM + h];
        wv[ht] = w2[h];
    }
    float* sb  = (float*)At;        // 256 floats (cross-wave partials)
    float* sbe = sb + 256;          // 64 floats (e per row)
    #pragma unroll
    for (int mt = 0; mt < 4; mt++) {
        #pragma unroll
        for (int r = 0; r < 4; r++) {
            float partial = 0.f;
            #pragma unroll
            for (int ht = 0; ht < 4; ht++) {
                float x = acc[mt][ht][r] + qp[ht];
                x = fminf(fmaxf(x, -15.f), 15.f);
                float e = __expf(2.f * x);
                partial += (e - 1.f) / (e + 1.f) * wv[ht];
            }
            #pragma unroll
            for (int o = 1; o < 16; o <<= 1) partial += __shfl_xor(partial, o);
            if (hl == 0) sb[wid * 64 + mt * 16 + lhi * 4 + r] = partial;
        }
    }
    __syncthreads();

    // ---- epilogue 2: score -> e = exp(score) (masked -> 0) ----
    if (tid < 64) {
        float s = sb[tid] + sb[64 + tid] + sb[128 + tid] + sb[192 + tid] + b2[0];
        int grow = row0 + tid;
        int bb = grow >> 11, ll = grow & 2047;
        float e = (mask[bb * 2048 + ll] == 1) ? 0.f : __expf(s);
        e_ws[grow] = e;
        sbe[tid] = e;
        float tot = e;
        #pragma unroll
        for (int o = 32; o; o >>= 1) tot += __shfl_down(tot, o);
        if (tid == 0) esum_ws[bid] = tot;
    }
    __syncthreads();

    // ---- epilogue 3: partial GEMV (tile is L2/L3-hot) ----
    {
        int d0 = tid * 4;
        const float* cb = ctx + (size_t)row0 * DDIM + d0;
        float4 a = {0.f, 0.f, 0.f, 0.f};
        #pragma unroll 8
        for (int l = 0; l < 64; l++) {
            float el = sbe[l];
            float4 cc = *(const float4*)(cb + (size_t)l * DDIM);
            a.x += el * cc.x; a.y += el * cc.y; a.z += el * cc.z; a.w += el * cc.w;
        }
        *(float4*)(part + (size_t)bid * DDIM + d0) = a;
    }
}

// ---------------- K3: normalize -> out_exp, out_p ----------------
__global__ __launch_bounds__(256) void k_norm(const float* __restrict__ e_ws,
                                              const float* __restrict__ esum_ws,
                                              const float* __restrict__ part,
                                              float* __restrict__ out_exp,
                                              float* __restrict__ out_p) {
    int b = blockIdx.x, dc = blockIdx.y;
    int tid = threadIdx.x;
    float se = 0.f;
    #pragma unroll
    for (int j = 0; j < 32; j++) se += esum_ws[b * 32 + j];
    float inv = 1.f / se;
    if (tid < 128) {
        int d = dc * 128 + tid;
        float s = 0.f;
        #pragma unroll
        for (int j = 0; j < 32; j++) s += part[(size_t)(b * 32 + j) * DDIM + d];
        out_exp[b * DDIM + d] = s * inv;
    }
    int l = dc * 256 + tid;
    out_p[b * LCTX + l] = e_ws[b * LCTX + l] * inv;
}

extern "C" void kernel_launch(void* const* d_in, const int* in_sizes, int n_in,
                              void* d_out, int out_size, void* d_ws, size_t ws_size,
                              hipStream_t stream) {
    const float* ctx   = (const float*)d_in[0];
    const float* query = (const float*)d_in[1];
    const int*   mask  = (const int*)d_in[2];
    const float* W1    = (const float*)d_in[3];
    const float* b1    = (const float*)d_in[4];
    const float* v     = (const float*)d_in[5];
    const float* g     = (const float*)d_in[6];
    const float* b2    = (const float*)d_in[7];
    float* out_exp = (float*)d_out;              // [16,1024]
    float* out_p   = (float*)d_out + 16384;      // [16,2048]

    char* ws = (char*)d_ws;
    unsigned short* Wc_sw = (unsigned short*)ws;          // 512 KB
    float* qproj = (float*)(ws + 524288);                 // 16 KB
    float* w2    = (float*)(ws + 540672);                 // 1 KB
    float* e_ws  = (float*)(ws + 541696);                 // 128 KB (16x2048)
    float* esum  = (float*)(ws + 672768);                 // 2 KB  (512)
    float* part  = (float*)(ws + 674816);                 // 2 MB  (512x1024)

    k_prep <<<dim3(1281),   256, 0, stream>>>(query, W1, b1, v, g, qproj, Wc_sw, w2);
    k_score<<<dim3(512),    256, 0, stream>>>(ctx, Wc_sw, qproj, w2, b2, mask, e_ws, esum, part);
    k_norm <<<dim3(16, 8),  256, 0, stream>>>(e_ws, esum, part, out_exp, out_p);
}